// Round 1
// baseline (1085.372 us; speedup 1.0000x reference)
//
#include <hip/hip_runtime.h>
#include <hip/hip_bf16.h>

// Problem constants (LegacyScan2DOperator): B=8, H=96, W=96, D=192, C=384.
#define NB 8
#define NH 96
#define NW 96
#define ND 192
#define NC 384
#define NPOS (NB*NH*NW)            // 73728 spatial positions
#define NELEM ((size_t)NPOS*NC)    // 28,311,552 proj/local elements

#define DECAY 0.6f
#define GAIN 0.4f

// ---------------- in_proj: [M,192] @ [192,384] + b, M-tile 8 ----------------
__global__ __launch_bounds__(384) void in_proj_kernel(
    const float* __restrict__ x, const float* __restrict__ Wi,
    const float* __restrict__ bi, float* __restrict__ proj) {
  __shared__ float xs[8 * ND];
  size_t m0 = (size_t)blockIdx.x * 8;
  for (int i = threadIdx.x; i < 8 * ND; i += 384) xs[i] = x[m0 * ND + i];
  __syncthreads();
  int c = threadIdx.x;
  float acc[8];
  float bb = bi[c];
#pragma unroll
  for (int i = 0; i < 8; ++i) acc[i] = bb;
  for (int k = 0; k < ND; ++k) {
    float w = Wi[(size_t)k * NC + c];
#pragma unroll
    for (int i = 0; i < 8; ++i) acc[i] += xs[i * ND + k] * w;
  }
#pragma unroll
  for (int i = 0; i < 8; ++i) proj[(m0 + i) * NC + c] = acc[i];
}

// ---------------- depthwise 3x3 SAME conv, channels-last --------------------
__global__ __launch_bounds__(256) void dwconv_kernel(
    const float* __restrict__ proj, const float* __restrict__ cw,
    float* __restrict__ loc) {
  size_t idx = (size_t)blockIdx.x * 256 + threadIdx.x;
  if (idx >= NELEM) return;
  int c = (int)(idx % NC);
  size_t pos = idx / NC;
  int w = (int)(pos % NW);
  size_t bh = pos / NW;
  int h = (int)(bh % NH);
  int b = (int)(bh / NH);
  float a = 0.f;
#pragma unroll
  for (int dh = -1; dh <= 1; ++dh) {
    int hh = h + dh;
    if (hh < 0 || hh >= NH) continue;
#pragma unroll
    for (int dw = -1; dw <= 1; ++dw) {
      int ww = w + dw;
      if (ww < 0 || ww >= NW) continue;
      a += proj[(((size_t)(b * NH + hh)) * NW + ww) * NC + c] *
           cw[c * 9 + (dh + 1) * 3 + (dw + 1)];
    }
  }
  loc[idx] = a;
}

// ------------- horizontal scans: acc = lr + rl  (thread per b,h,c) ----------
__global__ __launch_bounds__(256) void hscan_kernel(
    const float* __restrict__ loc, float* __restrict__ acc) {
  size_t t = (size_t)blockIdx.x * 256 + threadIdx.x;  // over B*H*C = 294912
  if (t >= (size_t)NB * NH * NC) return;
  int c = (int)(t % NC);
  int bh = (int)(t / NC);                       // b*NH + h
  size_t base = (size_t)bh * NW * NC + c;       // w stride = NC
  float s = 0.f;
  for (int w = 0; w < NW; ++w) {
    size_t i = base + (size_t)w * NC;
    s = DECAY * s + GAIN * loc[i];
    acc[i] = s;
  }
  s = 0.f;
  for (int w = NW - 1; w >= 0; --w) {
    size_t i = base + (size_t)w * NC;
    s = DECAY * s + GAIN * loc[i];
    acc[i] += s;
  }
}

// -- vertical scans + final mix: acc = local + 0.25*(acc + tb + bt) ----------
__global__ __launch_bounds__(256) void vscan_kernel(
    const float* __restrict__ loc, float* __restrict__ acc) {
  size_t t = (size_t)blockIdx.x * 256 + threadIdx.x;  // over B*W*C = 294912
  if (t >= (size_t)NB * NW * NC) return;
  int c = (int)(t % NC);
  int bw = (int)(t / NC);
  int w = bw % NW;
  int b = bw / NW;
  size_t base = ((size_t)b * NH * NW + w) * NC + c;   // h stride = NW*NC
  float s = 0.f;
  for (int h = 0; h < NH; ++h) {
    size_t i = base + (size_t)h * NW * NC;
    s = DECAY * s + GAIN * loc[i];
    acc[i] += s;                       // acc = lr+rl+tb
  }
  s = 0.f;
  for (int h = NH - 1; h >= 0; --h) {
    size_t i = base + (size_t)h * NW * NC;
    float xv = loc[i];
    s = DECAY * s + GAIN * xv;
    acc[i] = xv + 0.25f * (acc[i] + s);  // local + 0.25*(lr+rl+tb+bt)
  }
}

// ---------------- layernorm over C (block per position) ---------------------
__global__ __launch_bounds__(384) void ln_kernel(
    const float* __restrict__ mixed, const float* __restrict__ g,
    const float* __restrict__ bb, float* __restrict__ nrm) {
  size_t m = blockIdx.x;
  int c = threadIdx.x;
  float v = mixed[m * NC + c];
  float s = v, s2 = v * v;
#pragma unroll
  for (int o = 32; o > 0; o >>= 1) {
    s += __shfl_down(s, o, 64);
    s2 += __shfl_down(s2, o, 64);
  }
  __shared__ float sh[12];
  __shared__ float mv[2];
  int wv = c >> 6;
  if ((c & 63) == 0) { sh[wv] = s; sh[6 + wv] = s2; }
  __syncthreads();
  if (c == 0) {
    float t = 0.f, t2 = 0.f;
    for (int i = 0; i < 6; ++i) { t += sh[i]; t2 += sh[6 + i]; }
    float mu = t * (1.f / NC);
    mv[0] = mu;
    mv[1] = t2 * (1.f / NC) - mu * mu;
  }
  __syncthreads();
  float mu = mv[0];
  float r = rsqrtf(mv[1] + 1e-5f);
  nrm[m * NC + c] = (v - mu) * r * g[c] + bb[c];
}

// ---------------- out_proj: [M,384] @ [384,192] + b, M-tile 8 ---------------
__global__ __launch_bounds__(192) void out_proj_kernel(
    const float* __restrict__ nrm, const float* __restrict__ Wo,
    const float* __restrict__ bo, float* __restrict__ out) {
  __shared__ float ns[8 * NC];
  size_t m0 = (size_t)blockIdx.x * 8;
  for (int i = threadIdx.x; i < 8 * NC; i += 192) ns[i] = nrm[m0 * NC + i];
  __syncthreads();
  int d = threadIdx.x;
  float acc[8];
  float bb = bo[d];
#pragma unroll
  for (int i = 0; i < 8; ++i) acc[i] = bb;
  for (int k = 0; k < NC; ++k) {
    float w = Wo[(size_t)k * ND + d];
#pragma unroll
    for (int i = 0; i < 8; ++i) acc[i] += ns[i * NC + k] * w;
  }
#pragma unroll
  for (int i = 0; i < 8; ++i) out[(m0 + i) * ND + d] = acc[i];
}

extern "C" void kernel_launch(void* const* d_in, const int* in_sizes, int n_in,
                              void* d_out, int out_size, void* d_ws, size_t ws_size,
                              hipStream_t stream) {
  const float* x    = (const float*)d_in[0];
  const float* W_in = (const float*)d_in[1];
  const float* b_in = (const float*)d_in[2];
  const float* cw   = (const float*)d_in[3];
  const float* ln_g = (const float*)d_in[4];
  const float* ln_b = (const float*)d_in[5];
  const float* W_out= (const float*)d_in[6];
  const float* b_out= (const float*)d_in[7];
  float* out = (float*)d_out;

  float* wsf   = (float*)d_ws;
  float* proj  = wsf;            // NELEM floats; later reused as scan acc/mixed
  float* loc   = wsf + NELEM;    // NELEM floats; later reused as normed
  float* acc   = proj;
  float* nrm   = loc;

  // 1) in_proj
  in_proj_kernel<<<NPOS / 8, 384, 0, stream>>>(x, W_in, b_in, proj);
  // 2) depthwise conv
  dwconv_kernel<<<(unsigned)((NELEM + 255) / 256), 256, 0, stream>>>(proj, cw, loc);
  // 3) horizontal EMA (lr+rl) into acc (overwrites proj)
  hscan_kernel<<<(NB * NH * NC + 255) / 256, 256, 0, stream>>>(loc, acc);
  // 4) vertical EMA + final mix into acc
  vscan_kernel<<<(NB * NW * NC + 255) / 256, 256, 0, stream>>>(loc, acc);
  // 5) layernorm into nrm (overwrites loc)
  ln_kernel<<<NPOS, 384, 0, stream>>>(acc, ln_g, ln_b, nrm);
  // 6) out_proj
  out_proj_kernel<<<NPOS / 8, 192, 0, stream>>>(nrm, W_out, b_out, out);
}

// Round 2
// 582.768 us; speedup vs baseline: 1.8624x; 1.8624x over previous
//
#include <hip/hip_runtime.h>
#include <hip/hip_bf16.h>

// Problem constants (LegacyScan2DOperator): B=8, H=96, W=96, D=192, C=384.
#define NB 8
#define NH 96
#define NW 96
#define ND 192
#define NC 384
#define NPOS (NB*NH*NW)            // 73728 spatial positions
#define NELEM ((size_t)NPOS*NC)    // 28,311,552 proj/local elements

#define DECAY 0.6f
#define GAIN 0.4f

typedef __attribute__((ext_vector_type(8))) short bf16x8;
typedef __attribute__((ext_vector_type(4))) float f32x4;

__device__ inline unsigned short f2bf(float f) {
  unsigned u = __float_as_uint(f);
  u += 0x7fff + ((u >> 16) & 1);          // RNE
  return (unsigned short)(u >> 16);
}

__device__ inline void gload16(const void* g, void* l) {
  __builtin_amdgcn_global_load_lds(
      (const __attribute__((address_space(1))) void*)g,
      (__attribute__((address_space(3))) void*)l, 16, 0, 0);
}

// ---------------- conversions ----------------------------------------------
__global__ __launch_bounds__(256) void cvt_x_kernel(
    const float* __restrict__ x, unsigned short* __restrict__ xb) {
  size_t i = ((size_t)blockIdx.x * 256 + threadIdx.x) * 4;  // NPOS*ND % 4 == 0
  float4 v = *reinterpret_cast<const float4*>(&x[i]);
  ushort4 o = make_ushort4(f2bf(v.x), f2bf(v.y), f2bf(v.z), f2bf(v.w));
  *reinterpret_cast<ushort4*>(&xb[i]) = o;
}

// W_in [K=192][C=384] -> WtI [384][192] bf16
__global__ __launch_bounds__(256) void cvt_wi_kernel(
    const float* __restrict__ W, unsigned short* __restrict__ Wt) {
  int idx = blockIdx.x * 256 + threadIdx.x;
  if (idx >= ND * NC) return;
  int k = idx / NC, c = idx % NC;
  Wt[c * ND + k] = f2bf(W[idx]);
}

// W_out [K=384][D=192] -> WtO [192][384] bf16
__global__ __launch_bounds__(256) void cvt_wo_kernel(
    const float* __restrict__ W, unsigned short* __restrict__ Wt) {
  int idx = blockIdx.x * 256 + threadIdx.x;
  if (idx >= NC * ND) return;
  int k = idx / ND, d = idx % ND;
  Wt[d * NC + k] = f2bf(W[idx]);
}

// ---------------- MFMA GEMM: C[M][N] = A[M][K] @ Bt[N][K]^T + bias ----------
// BM=128, BK=32, 256 threads (4 waves as 2x2), wave tile 64 x (BN/2).
// LDS layout k-group-outer: slot(kg, r) = kg*ROWS + r, 8 bf16 per slot.
template<int K, int N, int BN>
__global__ __launch_bounds__(256) void gemm_kernel(
    const unsigned short* __restrict__ A,
    const unsigned short* __restrict__ Bt,
    const float* __restrict__ bias,
    float* __restrict__ C) {
  constexpr int NF = BN / 32;          // n-fragments per wave
  constexpr int BSLOTS = 4 * BN;
  __shared__ __align__(16) unsigned short lsA[4 * 128 * 8];
  __shared__ __align__(16) unsigned short lsB[BSLOTS * 8];

  const int tid = threadIdx.x;
  const int lane = tid & 63;
  const int wid = tid >> 6;
  const int wm = wid >> 1, wn = wid & 1;
  const int kg = lane >> 4, r16 = lane & 15;
  const int m0 = blockIdx.x * 128;
  const int n0 = blockIdx.y * BN;

  // staging sources (per-thread global addresses; LDS dest is lane-linear)
  const int sa0 = tid, sa1 = tid + 256;
  const unsigned short* srcA0 = A + (size_t)(m0 + (sa0 & 127)) * K + (sa0 >> 7) * 8;
  const unsigned short* srcA1 = A + (size_t)(m0 + (sa1 & 127)) * K + (sa1 >> 7) * 8;
  const unsigned short* srcB0 = Bt + (size_t)(n0 + (tid & (BN - 1))) * K + (tid / BN) * 8;
  const unsigned short* srcBh = Bt;
  if constexpr (BN == 128) {
    const int sb1 = tid + 256;
    srcBh = Bt + (size_t)(n0 + (sb1 & 127)) * K + (sb1 >> 7) * 8;
  }

  // fragment LDS offsets (fixed across k-steps)
  int aoff[4], boff[NF];
#pragma unroll
  for (int m = 0; m < 4; ++m)
    aoff[m] = (kg * 128 + wm * 64 + m * 16 + r16) * 8;
#pragma unroll
  for (int n = 0; n < NF; ++n)
    boff[n] = (kg * BN + wn * (BN / 2) + n * 16 + r16) * 8;

  f32x4 acc[4][NF];
  float bv[NF];
#pragma unroll
  for (int n = 0; n < NF; ++n) bv[n] = bias[n0 + wn * (BN / 2) + n * 16 + r16];
#pragma unroll
  for (int m = 0; m < 4; ++m)
#pragma unroll
    for (int n = 0; n < NF; ++n)
      acc[m][n] = (f32x4){bv[n], bv[n], bv[n], bv[n]};

  for (int ks = 0; ks < K / 32; ++ks) {
    const int ke = ks * 32;
    gload16(srcA0 + ke, &lsA[sa0 * 8]);
    gload16(srcA1 + ke, &lsA[sa1 * 8]);
    gload16(srcB0 + ke, &lsB[tid * 8]);
    if constexpr (BN == 128) gload16(srcBh + ke, &lsB[(tid + 256) * 8]);
    __syncthreads();   // compiler drains vmcnt before s_barrier
    bf16x8 af[4], bfr[NF];
#pragma unroll
    for (int m = 0; m < 4; ++m)
      af[m] = *reinterpret_cast<const bf16x8*>(&lsA[aoff[m]]);
#pragma unroll
    for (int n = 0; n < NF; ++n)
      bfr[n] = *reinterpret_cast<const bf16x8*>(&lsB[boff[n]]);
#pragma unroll
    for (int m = 0; m < 4; ++m)
#pragma unroll
      for (int n = 0; n < NF; ++n)
        acc[m][n] = __builtin_amdgcn_mfma_f32_16x16x32_bf16(af[m], bfr[n], acc[m][n], 0, 0, 0);
    __syncthreads();
  }

  // C/D layout: col = lane&15, row = (lane>>4)*4 + j   [m89/m91 verified]
#pragma unroll
  for (int m = 0; m < 4; ++m) {
    const int row = m0 + wm * 64 + m * 16 + kg * 4;
#pragma unroll
    for (int n = 0; n < NF; ++n) {
      const int col = n0 + wn * (BN / 2) + n * 16 + r16;
#pragma unroll
      for (int j = 0; j < 4; ++j)
        C[(size_t)(row + j) * N + col] = acc[m][n][j];
    }
  }
}

// ---------------- depthwise 3x3 SAME conv, channels-last --------------------
__global__ __launch_bounds__(256) void dwconv_kernel(
    const float* __restrict__ proj, const float* __restrict__ cw,
    float* __restrict__ loc) {
  size_t idx = (size_t)blockIdx.x * 256 + threadIdx.x;
  if (idx >= NELEM) return;
  int c = (int)(idx % NC);
  size_t pos = idx / NC;
  int w = (int)(pos % NW);
  size_t bh = pos / NW;
  int h = (int)(bh % NH);
  int b = (int)(bh / NH);
  float a = 0.f;
#pragma unroll
  for (int dh = -1; dh <= 1; ++dh) {
    int hh = h + dh;
    if (hh < 0 || hh >= NH) continue;
#pragma unroll
    for (int dw = -1; dw <= 1; ++dw) {
      int ww = w + dw;
      if (ww < 0 || ww >= NW) continue;
      a += proj[(((size_t)(b * NH + hh)) * NW + ww) * NC + c] *
           cw[c * 9 + (dh + 1) * 3 + (dw + 1)];
    }
  }
  loc[idx] = a;
}

// ------------- horizontal scans: acc = lr + rl  (thread per b,h,c) ----------
__global__ __launch_bounds__(256) void hscan_kernel(
    const float* __restrict__ loc, float* __restrict__ acc) {
  size_t t = (size_t)blockIdx.x * 256 + threadIdx.x;
  if (t >= (size_t)NB * NH * NC) return;
  int c = (int)(t % NC);
  int bh = (int)(t / NC);
  size_t base = (size_t)bh * NW * NC + c;
  float s = 0.f;
  for (int w = 0; w < NW; ++w) {
    size_t i = base + (size_t)w * NC;
    s = DECAY * s + GAIN * loc[i];
    acc[i] = s;
  }
  s = 0.f;
  for (int w = NW - 1; w >= 0; --w) {
    size_t i = base + (size_t)w * NC;
    s = DECAY * s + GAIN * loc[i];
    acc[i] += s;
  }
}

// -- vertical scans + final mix: acc = local + 0.25*(acc + tb + bt) ----------
__global__ __launch_bounds__(256) void vscan_kernel(
    const float* __restrict__ loc, float* __restrict__ acc) {
  size_t t = (size_t)blockIdx.x * 256 + threadIdx.x;
  if (t >= (size_t)NB * NW * NC) return;
  int c = (int)(t % NC);
  int bw = (int)(t / NC);
  int w = bw % NW;
  int b = bw / NW;
  size_t base = ((size_t)b * NH * NW + w) * NC + c;
  float s = 0.f;
  for (int h = 0; h < NH; ++h) {
    size_t i = base + (size_t)h * NW * NC;
    s = DECAY * s + GAIN * loc[i];
    acc[i] += s;
  }
  s = 0.f;
  for (int h = NH - 1; h >= 0; --h) {
    size_t i = base + (size_t)h * NW * NC;
    float xv = loc[i];
    s = DECAY * s + GAIN * xv;
    acc[i] = xv + 0.25f * (acc[i] + s);
  }
}

// ---------------- layernorm over C (block per position) -> bf16 -------------
__global__ __launch_bounds__(384) void ln_kernel(
    const float* __restrict__ mixed, const float* __restrict__ g,
    const float* __restrict__ bb, unsigned short* __restrict__ nrm) {
  size_t m = blockIdx.x;
  int c = threadIdx.x;
  float v = mixed[m * NC + c];
  float s = v, s2 = v * v;
#pragma unroll
  for (int o = 32; o > 0; o >>= 1) {
    s += __shfl_down(s, o, 64);
    s2 += __shfl_down(s2, o, 64);
  }
  __shared__ float sh[12];
  __shared__ float mv[2];
  int wv = c >> 6;
  if ((c & 63) == 0) { sh[wv] = s; sh[6 + wv] = s2; }
  __syncthreads();
  if (c == 0) {
    float t = 0.f, t2 = 0.f;
    for (int i = 0; i < 6; ++i) { t += sh[i]; t2 += sh[6 + i]; }
    float mu = t * (1.f / NC);
    mv[0] = mu;
    mv[1] = t2 * (1.f / NC) - mu * mu;
  }
  __syncthreads();
  float mu = mv[0];
  float r = rsqrtf(mv[1] + 1e-5f);
  nrm[m * NC + c] = f2bf((v - mu) * r * g[c] + bb[c]);
}

extern "C" void kernel_launch(void* const* d_in, const int* in_sizes, int n_in,
                              void* d_out, int out_size, void* d_ws, size_t ws_size,
                              hipStream_t stream) {
  const float* x    = (const float*)d_in[0];
  const float* W_in = (const float*)d_in[1];
  const float* b_in = (const float*)d_in[2];
  const float* cw   = (const float*)d_in[3];
  const float* ln_g = (const float*)d_in[4];
  const float* ln_b = (const float*)d_in[5];
  const float* W_out= (const float*)d_in[6];
  const float* b_out= (const float*)d_in[7];
  float* out = (float*)d_out;

  float* wsf  = (float*)d_ws;
  float* proj = wsf;                 // [NELEM] f32; reused as scan acc / mixed
  float* loc  = wsf + NELEM;         // [NELEM] f32 region, multi-purpose:
  unsigned short* xb  = (unsigned short*)loc;               // bf16 x (pre-dwconv)
  unsigned short* WtI = (unsigned short*)(loc + NELEM / 2); // bf16 W_in^T (pre-dwconv)
  unsigned short* nb  = (unsigned short*)loc;               // bf16 normed (post-vscan)
  unsigned short* WtO = (unsigned short*)(loc + NELEM / 2); // bf16 W_out^T (post-vscan)
  float* acc = proj;

  // 1) conversions for in_proj
  cvt_x_kernel<<<(NPOS * ND / 4) / 256, 256, 0, stream>>>(x, xb);
  cvt_wi_kernel<<<(ND * NC + 255) / 256, 256, 0, stream>>>(W_in, WtI);
  // 2) in_proj MFMA GEMM: proj = xb @ W_in + b_in   [M=73728, K=192, N=384]
  {
    dim3 g(NPOS / 128, NC / 128);
    gemm_kernel<ND, NC, 128><<<g, 256, 0, stream>>>(xb, WtI, b_in, proj);
  }
  // 3) depthwise conv (overwrites loc region; xb/WtI dead)
  dwconv_kernel<<<(unsigned)((NELEM + 255) / 256), 256, 0, stream>>>(proj, cw, loc);
  // 4) horizontal EMA (lr+rl) into acc (overwrites proj)
  hscan_kernel<<<(NB * NH * NC + 255) / 256, 256, 0, stream>>>(loc, acc);
  // 5) vertical EMA + final mix into acc
  vscan_kernel<<<(NB * NW * NC + 255) / 256, 256, 0, stream>>>(loc, acc);
  // 6) W_out^T bf16 (loc region dead now)
  cvt_wo_kernel<<<(NC * ND + 255) / 256, 256, 0, stream>>>(W_out, WtO);
  // 7) layernorm -> bf16 normed
  ln_kernel<<<NPOS, NC, 0, stream>>>(acc, ln_g, ln_b, nb);
  // 8) out_proj MFMA GEMM: out = nb @ W_out + b_out  [M=73728, K=384, N=192]
  {
    dim3 g(NPOS / 128, ND / 64);
    gemm_kernel<NC, ND, 64><<<g, 256, 0, stream>>>(nb, WtO, b_out, out);
  }
}

// Round 3
// 367.232 us; speedup vs baseline: 2.9556x; 1.5869x over previous
//
#include <hip/hip_runtime.h>
#include <hip/hip_bf16.h>

// Problem constants (LegacyScan2DOperator): B=8, H=96, W=96, D=192, C=384.
#define NB 8
#define NH 96
#define NW 96
#define ND 192
#define NC 384
#define NPOS (NB*NH*NW)            // 73728 spatial positions
#define NELEM ((size_t)NPOS*NC)    // 28,311,552 proj/local elements

#define DECAY 0.6f
#define GAIN 0.4f

typedef __attribute__((ext_vector_type(8))) short bf16x8;
typedef __attribute__((ext_vector_type(4))) float f32x4;

__device__ inline unsigned short f2bf(float f) {
  unsigned u = __float_as_uint(f);
  u += 0x7fff + ((u >> 16) & 1);          // RNE
  return (unsigned short)(u >> 16);
}

__device__ inline void gload16(const void* g, void* l) {
  __builtin_amdgcn_global_load_lds(
      (const __attribute__((address_space(1))) void*)g,
      (__attribute__((address_space(3))) void*)l, 16, 0, 0);
}

__device__ inline f32x4 ldf4(const float* p) {
  return *reinterpret_cast<const f32x4*>(p);
}

// ---------------- conversions ----------------------------------------------
__global__ __launch_bounds__(256) void cvt_x_kernel(
    const float* __restrict__ x, unsigned short* __restrict__ xb) {
  size_t i = ((size_t)blockIdx.x * 256 + threadIdx.x) * 4;
  float4 v = *reinterpret_cast<const float4*>(&x[i]);
  ushort4 o = make_ushort4(f2bf(v.x), f2bf(v.y), f2bf(v.z), f2bf(v.w));
  *reinterpret_cast<ushort4*>(&xb[i]) = o;
}

// W_in [K=192][C=384] -> WtI [384][192] bf16
__global__ __launch_bounds__(256) void cvt_wi_kernel(
    const float* __restrict__ W, unsigned short* __restrict__ Wt) {
  int idx = blockIdx.x * 256 + threadIdx.x;
  if (idx >= ND * NC) return;
  int k = idx / NC, c = idx % NC;
  Wt[c * ND + k] = f2bf(W[idx]);
}

// W_out [K=384][D=192] -> WtO [192][384] bf16
__global__ __launch_bounds__(256) void cvt_wo_kernel(
    const float* __restrict__ W, unsigned short* __restrict__ Wt) {
  int idx = blockIdx.x * 256 + threadIdx.x;
  if (idx >= NC * ND) return;
  int k = idx / ND, d = idx % ND;
  Wt[d * NC + k] = f2bf(W[idx]);
}

// ---------------- MFMA GEMM: C[M][N] = A[M][K] @ Bt[N][K]^T + bias ----------
template<int K, int N, int BN>
__global__ __launch_bounds__(256) void gemm_kernel(
    const unsigned short* __restrict__ A,
    const unsigned short* __restrict__ Bt,
    const float* __restrict__ bias,
    float* __restrict__ C) {
  constexpr int NF = BN / 32;
  constexpr int BSLOTS = 4 * BN;
  __shared__ __align__(16) unsigned short lsA[4 * 128 * 8];
  __shared__ __align__(16) unsigned short lsB[BSLOTS * 8];

  const int tid = threadIdx.x;
  const int lane = tid & 63;
  const int wid = tid >> 6;
  const int wm = wid >> 1, wn = wid & 1;
  const int kg = lane >> 4, r16 = lane & 15;
  const int m0 = blockIdx.x * 128;
  const int n0 = blockIdx.y * BN;

  const int sa0 = tid, sa1 = tid + 256;
  const unsigned short* srcA0 = A + (size_t)(m0 + (sa0 & 127)) * K + (sa0 >> 7) * 8;
  const unsigned short* srcA1 = A + (size_t)(m0 + (sa1 & 127)) * K + (sa1 >> 7) * 8;
  const unsigned short* srcB0 = Bt + (size_t)(n0 + (tid & (BN - 1))) * K + (tid / BN) * 8;
  const unsigned short* srcBh = Bt;
  if constexpr (BN == 128) {
    const int sb1 = tid + 256;
    srcBh = Bt + (size_t)(n0 + (sb1 & 127)) * K + (sb1 >> 7) * 8;
  }

  int aoff[4], boff[NF];
#pragma unroll
  for (int m = 0; m < 4; ++m)
    aoff[m] = (kg * 128 + wm * 64 + m * 16 + r16) * 8;
#pragma unroll
  for (int n = 0; n < NF; ++n)
    boff[n] = (kg * BN + wn * (BN / 2) + n * 16 + r16) * 8;

  f32x4 acc[4][NF];
  float bv[NF];
#pragma unroll
  for (int n = 0; n < NF; ++n) bv[n] = bias[n0 + wn * (BN / 2) + n * 16 + r16];
#pragma unroll
  for (int m = 0; m < 4; ++m)
#pragma unroll
    for (int n = 0; n < NF; ++n)
      acc[m][n] = (f32x4){bv[n], bv[n], bv[n], bv[n]};

  for (int ks = 0; ks < K / 32; ++ks) {
    const int ke = ks * 32;
    gload16(srcA0 + ke, &lsA[sa0 * 8]);
    gload16(srcA1 + ke, &lsA[sa1 * 8]);
    gload16(srcB0 + ke, &lsB[tid * 8]);
    if constexpr (BN == 128) gload16(srcBh + ke, &lsB[(tid + 256) * 8]);
    __syncthreads();
    bf16x8 af[4], bfr[NF];
#pragma unroll
    for (int m = 0; m < 4; ++m)
      af[m] = *reinterpret_cast<const bf16x8*>(&lsA[aoff[m]]);
#pragma unroll
    for (int n = 0; n < NF; ++n)
      bfr[n] = *reinterpret_cast<const bf16x8*>(&lsB[boff[n]]);
#pragma unroll
    for (int m = 0; m < 4; ++m)
#pragma unroll
      for (int n = 0; n < NF; ++n)
        acc[m][n] = __builtin_amdgcn_mfma_f32_16x16x32_bf16(af[m], bfr[n], acc[m][n], 0, 0, 0);
    __syncthreads();
  }

#pragma unroll
  for (int m = 0; m < 4; ++m) {
    const int row = m0 + wm * 64 + m * 16 + kg * 4;
#pragma unroll
    for (int n = 0; n < NF; ++n) {
      const int col = n0 + wn * (BN / 2) + n * 16 + r16;
#pragma unroll
      for (int j = 0; j < 4; ++j)
        C[(size_t)(row + j) * N + col] = acc[m][n][j];
    }
  }
}

// ------------- depthwise 3x3 SAME conv, float4 over channels ----------------
__global__ __launch_bounds__(256) void dwconv_kernel(
    const float* __restrict__ proj, const float* __restrict__ cw,
    float* __restrict__ loc) {
  size_t idx = (size_t)blockIdx.x * 256 + threadIdx.x;   // over NELEM/4
  int c4 = (int)(idx % (NC / 4));
  size_t pos = idx / (NC / 4);
  int w = (int)(pos % NW);
  size_t bh = pos / NW;
  int h = (int)(bh % NH);
  int b = (int)(bh / NH);

  // weights for channels c4*4..c4*4+3: 36 contiguous floats, 16B-aligned
  f32x4 q[9];
  const float* cwp = cw + (size_t)c4 * 36;
#pragma unroll
  for (int i = 0; i < 9; ++i) q[i] = ldf4(cwp + i * 4);

  f32x4 a = {0.f, 0.f, 0.f, 0.f};
#pragma unroll
  for (int dh = -1; dh <= 1; ++dh) {
    int hh = h + dh;
    if (hh < 0 || hh >= NH) continue;
#pragma unroll
    for (int dw = -1; dw <= 1; ++dw) {
      int ww = w + dw;
      if (ww < 0 || ww >= NW) continue;
      const int tp = (dh + 1) * 3 + (dw + 1);
      f32x4 p = ldf4(proj + (((size_t)(b * NH + hh)) * NW + ww) * NC + c4 * 4);
      a[0] += p[0] * q[(0 + tp) >> 2][(0 + tp) & 3];
      a[1] += p[1] * q[(9 + tp) >> 2][(9 + tp) & 3];
      a[2] += p[2] * q[(18 + tp) >> 2][(18 + tp) & 3];
      a[3] += p[3] * q[(27 + tp) >> 2][(27 + tp) & 3];
    }
  }
  *reinterpret_cast<f32x4*>(loc + idx * 4) = a;
}

// ------------- horizontal scans, segmented: acc = lr + rl -------------------
// thread = (bh row, c4 chunk, 16-wide w segment); 16-step warmup (err ~ 0.6^16)
__global__ __launch_bounds__(256) void hscan_kernel(
    const float* __restrict__ loc, float* __restrict__ acc) {
  int t = blockIdx.x * 256 + threadIdx.x;      // 768*96*6 = 442368
  int c4 = t % 96;
  int seg = (t / 96) % 6;
  int bh = t / 576;
  const size_t base = (size_t)bh * (NW * NC) + c4 * 4;
  const float* rp = loc + base;
  float* ap = acc + base;
  const int w0 = seg * 16;

  f32x4 s = {0.f, 0.f, 0.f, 0.f};
  for (int w = (w0 >= 16 ? w0 - 16 : 0); w < w0; ++w)
    s = DECAY * s + GAIN * ldf4(rp + (size_t)w * NC);
  f32x4 fw[16];
#pragma unroll
  for (int i = 0; i < 16; ++i) {
    s = DECAY * s + GAIN * ldf4(rp + (size_t)(w0 + i) * NC);
    fw[i] = s;
  }
  s = (f32x4){0.f, 0.f, 0.f, 0.f};
  {
    int wend = w0 + 31 > 95 ? 95 : w0 + 31;
    for (int w = wend; w >= w0 + 16; --w)
      s = DECAY * s + GAIN * ldf4(rp + (size_t)w * NC);
  }
#pragma unroll
  for (int i = 15; i >= 0; --i) {
    s = DECAY * s + GAIN * ldf4(rp + (size_t)(w0 + i) * NC);
    *reinterpret_cast<f32x4*>(ap + (size_t)(w0 + i) * NC) = fw[i] + s;
  }
}

// -- vertical scans + final mix: acc = loc + 0.25*(acc + tb + bt) ------------
__global__ __launch_bounds__(256) void vscan_kernel(
    const float* __restrict__ loc, float* __restrict__ acc) {
  int t = blockIdx.x * 256 + threadIdx.x;      // 8*96*96*6 = 442368
  int c4 = t % 96;
  int w = (t / 96) % 96;
  int hseg = (t / 9216) % 6;
  int b = t / 55296;
  const size_t base = ((size_t)(b * NH) * NW + w) * NC + c4 * 4;
  const size_t hst = (size_t)NW * NC;
  const float* lp = loc + base;
  float* ap = acc + base;
  const int h0 = hseg * 16;

  f32x4 s = {0.f, 0.f, 0.f, 0.f};
  for (int h = (h0 >= 16 ? h0 - 16 : 0); h < h0; ++h)
    s = DECAY * s + GAIN * ldf4(lp + (size_t)h * hst);
  f32x4 tv[16];
#pragma unroll
  for (int i = 0; i < 16; ++i) {
    s = DECAY * s + GAIN * ldf4(lp + (size_t)(h0 + i) * hst);
    tv[i] = s;
  }
  s = (f32x4){0.f, 0.f, 0.f, 0.f};
  {
    int hend = h0 + 31 > 95 ? 95 : h0 + 31;
    for (int h = hend; h >= h0 + 16; --h)
      s = DECAY * s + GAIN * ldf4(lp + (size_t)h * hst);
  }
#pragma unroll
  for (int i = 15; i >= 0; --i) {
    size_t o = (size_t)(h0 + i) * hst;
    f32x4 xv = ldf4(lp + o);
    s = DECAY * s + GAIN * xv;
    f32x4 av = ldf4(ap + o);
    *reinterpret_cast<f32x4*>(ap + o) = xv + 0.25f * (av + tv[i] + s);
  }
}

// ---------------- layernorm over C, wave per position -> bf16 ---------------
__global__ __launch_bounds__(384) void ln_kernel(
    const float* __restrict__ mixed, const float* __restrict__ g,
    const float* __restrict__ bb, unsigned short* __restrict__ nrm) {
  int wv = threadIdx.x >> 6, lane = threadIdx.x & 63;
  size_t m = (size_t)blockIdx.x * 6 + wv;
  const int cb = lane * 6;
  const float* row = mixed + m * NC + cb;
  float v[6];
  *reinterpret_cast<float2*>(&v[0]) = *reinterpret_cast<const float2*>(row);
  *reinterpret_cast<float2*>(&v[2]) = *reinterpret_cast<const float2*>(row + 2);
  *reinterpret_cast<float2*>(&v[4]) = *reinterpret_cast<const float2*>(row + 4);
  float s = 0.f, s2 = 0.f;
#pragma unroll
  for (int i = 0; i < 6; ++i) { s += v[i]; s2 += v[i] * v[i]; }
#pragma unroll
  for (int o = 32; o > 0; o >>= 1) {
    s += __shfl_xor(s, o, 64);
    s2 += __shfl_xor(s2, o, 64);
  }
  float mu = s * (1.f / NC);
  float r = rsqrtf(s2 * (1.f / NC) - mu * mu + 1e-5f);
  unsigned short o6[6];
#pragma unroll
  for (int i = 0; i < 6; ++i)
    o6[i] = f2bf((v[i] - mu) * r * g[cb + i] + bb[cb + i]);
  unsigned short* op = nrm + m * NC + cb;
  *reinterpret_cast<ushort2*>(op)     = (ushort2){o6[0], o6[1]};
  *reinterpret_cast<ushort2*>(op + 2) = (ushort2){o6[2], o6[3]};
  *reinterpret_cast<ushort2*>(op + 4) = (ushort2){o6[4], o6[5]};
}

extern "C" void kernel_launch(void* const* d_in, const int* in_sizes, int n_in,
                              void* d_out, int out_size, void* d_ws, size_t ws_size,
                              hipStream_t stream) {
  const float* x    = (const float*)d_in[0];
  const float* W_in = (const float*)d_in[1];
  const float* b_in = (const float*)d_in[2];
  const float* cw   = (const float*)d_in[3];
  const float* ln_g = (const float*)d_in[4];
  const float* ln_b = (const float*)d_in[5];
  const float* W_out= (const float*)d_in[6];
  const float* b_out= (const float*)d_in[7];
  float* out = (float*)d_out;

  float* wsf  = (float*)d_ws;
  float* proj = wsf;                 // [NELEM] f32; reused as scan acc / mixed
  float* loc  = wsf + NELEM;         // [NELEM] f32 region, multi-purpose:
  unsigned short* xb  = (unsigned short*)loc;               // bf16 x (pre-dwconv)
  unsigned short* WtI = (unsigned short*)(loc + NELEM / 2); // bf16 W_in^T (pre-dwconv)
  unsigned short* nb  = (unsigned short*)loc;               // bf16 normed (post-vscan)
  unsigned short* WtO = (unsigned short*)(loc + NELEM / 2); // bf16 W_out^T (post-vscan)
  float* acc = proj;

  // 1) conversions for in_proj
  cvt_x_kernel<<<(NPOS * ND / 4) / 256, 256, 0, stream>>>(x, xb);
  cvt_wi_kernel<<<(ND * NC + 255) / 256, 256, 0, stream>>>(W_in, WtI);
  // 2) in_proj MFMA GEMM: proj = xb @ W_in + b_in   [M=73728, K=192, N=384]
  {
    dim3 g(NPOS / 128, NC / 128);
    gemm_kernel<ND, NC, 128><<<g, 256, 0, stream>>>(xb, WtI, b_in, proj);
  }
  // 3) depthwise conv (overwrites loc region; xb/WtI dead)
  dwconv_kernel<<<(unsigned)((NELEM / 4) / 256), 256, 0, stream>>>(proj, cw, loc);
  // 4) horizontal EMA (lr+rl) into acc (overwrites proj)
  hscan_kernel<<<(NB * NH * 96 * 6) / 256, 256, 0, stream>>>(loc, acc);
  // 5) vertical EMA + final mix into acc
  vscan_kernel<<<(NB * NW * 96 * 6) / 256, 256, 0, stream>>>(loc, acc);
  // 6) W_out^T bf16 (loc region dead now)
  cvt_wo_kernel<<<(NC * ND + 255) / 256, 256, 0, stream>>>(W_out, WtO);
  // 7) layernorm -> bf16 normed
  ln_kernel<<<NPOS / 6, 384, 0, stream>>>(acc, ln_g, ln_b, nb);
  // 8) out_proj MFMA GEMM: out = nb @ W_out + b_out  [M=73728, K=384, N=192]
  {
    dim3 g(NPOS / 128, ND / 64);
    gemm_kernel<NC, ND, 64><<<g, 256, 0, stream>>>(nb, WtO, b_out, out);
  }
}

// Round 4
// 301.711 us; speedup vs baseline: 3.5974x; 1.2172x over previous
//
#include <hip/hip_runtime.h>
#include <hip/hip_bf16.h>

// Problem constants (LegacyScan2DOperator): B=8, H=96, W=96, D=192, C=384.
#define NB 8
#define NH 96
#define NW 96
#define ND 192
#define NC 384
#define NPOS (NB*NH*NW)            // 73728 spatial positions
#define NELEM ((size_t)NPOS*NC)    // 28,311,552 proj/local elements

#define DECAY 0.6f
#define GAIN 0.4f

typedef __attribute__((ext_vector_type(8))) short bf16x8;
typedef __attribute__((ext_vector_type(4))) float f32x4;
typedef __attribute__((ext_vector_type(8))) float f32x8;
typedef __attribute__((ext_vector_type(4))) unsigned short us4;
typedef __attribute__((ext_vector_type(8))) unsigned short us8;

__device__ inline unsigned short f2bf(float f) {
  unsigned u = __float_as_uint(f);
  u += 0x7fff + ((u >> 16) & 1);          // RNE
  return (unsigned short)(u >> 16);
}
__device__ inline float bf2f(unsigned short u) {
  return __uint_as_float((unsigned)u << 16);
}

__device__ inline void gload16(const void* g, void* l) {
  __builtin_amdgcn_global_load_lds(
      (const __attribute__((address_space(1))) void*)g,
      (__attribute__((address_space(3))) void*)l, 16, 0, 0);
}

__device__ inline f32x4 ldf4(const float* p) {
  return *reinterpret_cast<const f32x4*>(p);
}
// load 4 bf16 channels -> f32x4
__device__ inline f32x4 ldb4(const unsigned short* p) {
  us4 v = *reinterpret_cast<const us4*>(p);
  return (f32x4){bf2f(v.x), bf2f(v.y), bf2f(v.z), bf2f(v.w)};
}
__device__ inline void stb4(unsigned short* p, f32x4 v) {
  us4 o = {f2bf(v[0]), f2bf(v[1]), f2bf(v[2]), f2bf(v[3])};
  *reinterpret_cast<us4*>(p) = o;
}

// ---------------- conversions ----------------------------------------------
__global__ __launch_bounds__(256) void cvt_x_kernel(
    const float* __restrict__ x, unsigned short* __restrict__ xb) {
  size_t i = ((size_t)blockIdx.x * 256 + threadIdx.x) * 4;
  float4 v = *reinterpret_cast<const float4*>(&x[i]);
  ushort4 o = make_ushort4(f2bf(v.x), f2bf(v.y), f2bf(v.z), f2bf(v.w));
  *reinterpret_cast<ushort4*>(&xb[i]) = o;
}

// W_in [K=192][C=384] -> WtI [384][192] bf16
__global__ __launch_bounds__(256) void cvt_wi_kernel(
    const float* __restrict__ W, unsigned short* __restrict__ Wt) {
  int idx = blockIdx.x * 256 + threadIdx.x;
  if (idx >= ND * NC) return;
  int k = idx / NC, c = idx % NC;
  Wt[c * ND + k] = f2bf(W[idx]);
}

// W_out [K=384][D=192] -> WtO [192][384] bf16
__global__ __launch_bounds__(256) void cvt_wo_kernel(
    const float* __restrict__ W, unsigned short* __restrict__ Wt) {
  int idx = blockIdx.x * 256 + threadIdx.x;
  if (idx >= NC * ND) return;
  int k = idx / ND, d = idx % ND;
  Wt[d * NC + k] = f2bf(W[idx]);
}

// ---------------- MFMA GEMM: C[M][N] = A[M][K] @ Bt[N][K]^T + bias ----------
// WRITE_BF16: emit bf16 output, else f32.
template<int K, int N, int BN, bool WRITE_BF16>
__global__ __launch_bounds__(256) void gemm_kernel(
    const unsigned short* __restrict__ A,
    const unsigned short* __restrict__ Bt,
    const float* __restrict__ bias,
    void* __restrict__ Cv) {
  constexpr int NF = BN / 32;
  constexpr int BSLOTS = 4 * BN;
  __shared__ __align__(16) unsigned short lsA[4 * 128 * 8];
  __shared__ __align__(16) unsigned short lsB[BSLOTS * 8];

  const int tid = threadIdx.x;
  const int lane = tid & 63;
  const int wid = tid >> 6;
  const int wm = wid >> 1, wn = wid & 1;
  const int kg = lane >> 4, r16 = lane & 15;
  const int m0 = blockIdx.x * 128;
  const int n0 = blockIdx.y * BN;

  const int sa0 = tid, sa1 = tid + 256;
  const unsigned short* srcA0 = A + (size_t)(m0 + (sa0 & 127)) * K + (sa0 >> 7) * 8;
  const unsigned short* srcA1 = A + (size_t)(m0 + (sa1 & 127)) * K + (sa1 >> 7) * 8;
  const unsigned short* srcB0 = Bt + (size_t)(n0 + (tid & (BN - 1))) * K + (tid / BN) * 8;
  const unsigned short* srcBh = Bt;
  if constexpr (BN == 128) {
    const int sb1 = tid + 256;
    srcBh = Bt + (size_t)(n0 + (sb1 & 127)) * K + (sb1 >> 7) * 8;
  }

  int aoff[4], boff[NF];
#pragma unroll
  for (int m = 0; m < 4; ++m)
    aoff[m] = (kg * 128 + wm * 64 + m * 16 + r16) * 8;
#pragma unroll
  for (int n = 0; n < NF; ++n)
    boff[n] = (kg * BN + wn * (BN / 2) + n * 16 + r16) * 8;

  f32x4 acc[4][NF];
  float bv[NF];
#pragma unroll
  for (int n = 0; n < NF; ++n) bv[n] = bias[n0 + wn * (BN / 2) + n * 16 + r16];
#pragma unroll
  for (int m = 0; m < 4; ++m)
#pragma unroll
    for (int n = 0; n < NF; ++n)
      acc[m][n] = (f32x4){bv[n], bv[n], bv[n], bv[n]};

  for (int ks = 0; ks < K / 32; ++ks) {
    const int ke = ks * 32;
    gload16(srcA0 + ke, &lsA[sa0 * 8]);
    gload16(srcA1 + ke, &lsA[sa1 * 8]);
    gload16(srcB0 + ke, &lsB[tid * 8]);
    if constexpr (BN == 128) gload16(srcBh + ke, &lsB[(tid + 256) * 8]);
    __syncthreads();
    bf16x8 af[4], bfr[NF];
#pragma unroll
    for (int m = 0; m < 4; ++m)
      af[m] = *reinterpret_cast<const bf16x8*>(&lsA[aoff[m]]);
#pragma unroll
    for (int n = 0; n < NF; ++n)
      bfr[n] = *reinterpret_cast<const bf16x8*>(&lsB[boff[n]]);
#pragma unroll
    for (int m = 0; m < 4; ++m)
#pragma unroll
      for (int n = 0; n < NF; ++n)
        acc[m][n] = __builtin_amdgcn_mfma_f32_16x16x32_bf16(af[m], bfr[n], acc[m][n], 0, 0, 0);
    __syncthreads();
  }

#pragma unroll
  for (int m = 0; m < 4; ++m) {
    const int row = m0 + wm * 64 + m * 16 + kg * 4;
#pragma unroll
    for (int n = 0; n < NF; ++n) {
      const int col = n0 + wn * (BN / 2) + n * 16 + r16;
#pragma unroll
      for (int j = 0; j < 4; ++j) {
        if constexpr (WRITE_BF16)
          ((unsigned short*)Cv)[(size_t)(row + j) * N + col] = f2bf(acc[m][n][j]);
        else
          ((float*)Cv)[(size_t)(row + j) * N + col] = acc[m][n][j];
      }
    }
  }
}

// ------- depthwise 3x3 SAME conv, bf16 in/out, 8 channels per thread --------
__global__ __launch_bounds__(256) void dwconv_kernel(
    const unsigned short* __restrict__ proj, const float* __restrict__ cw,
    unsigned short* __restrict__ loc) {
  size_t idx = (size_t)blockIdx.x * 256 + threadIdx.x;   // over NELEM/8
  int c8 = (int)(idx % (NC / 8));
  size_t pos = idx / (NC / 8);
  int w = (int)(pos % NW);
  size_t bh = pos / NW;
  int h = (int)(bh % NH);
  int b = (int)(bh / NH);

  // weights for channels c8*8..c8*8+7: 72 contiguous floats
  f32x4 q[18];
  const float* cwp = cw + (size_t)c8 * 72;
#pragma unroll
  for (int i = 0; i < 18; ++i) q[i] = ldf4(cwp + i * 4);

  f32x8 a = {0.f, 0.f, 0.f, 0.f, 0.f, 0.f, 0.f, 0.f};
#pragma unroll
  for (int dh = -1; dh <= 1; ++dh) {
    int hh = h + dh;
    if (hh < 0 || hh >= NH) continue;
#pragma unroll
    for (int dw = -1; dw <= 1; ++dw) {
      int ww = w + dw;
      if (ww < 0 || ww >= NW) continue;
      const int tp = (dh + 1) * 3 + (dw + 1);
      us8 p = *reinterpret_cast<const us8*>(
          proj + (((size_t)(b * NH + hh)) * NW + ww) * NC + c8 * 8);
#pragma unroll
      for (int c = 0; c < 8; ++c)
        a[c] += bf2f(p[c]) * q[(c * 9 + tp) >> 2][(c * 9 + tp) & 3];
    }
  }
  us8 o;
#pragma unroll
  for (int c = 0; c < 8; ++c) o[c] = f2bf(a[c]);
  *reinterpret_cast<us8*>(loc + idx * 8) = o;
}

// ------------- horizontal scans, segmented: acc = lr + rl (bf16) ------------
__global__ __launch_bounds__(256) void hscan_kernel(
    const unsigned short* __restrict__ loc, unsigned short* __restrict__ acc) {
  int t = blockIdx.x * 256 + threadIdx.x;      // 768*96*6 = 442368
  int c4 = t % 96;
  int seg = (t / 96) % 6;
  int bh = t / 576;
  const size_t base = (size_t)bh * (NW * NC) + c4 * 4;
  const unsigned short* rp = loc + base;
  unsigned short* ap = acc + base;
  const int w0 = seg * 16;

  f32x4 s = {0.f, 0.f, 0.f, 0.f};
  for (int w = (w0 >= 16 ? w0 - 16 : 0); w < w0; ++w)
    s = DECAY * s + GAIN * ldb4(rp + (size_t)w * NC);
  f32x4 fw[16];
#pragma unroll
  for (int i = 0; i < 16; ++i) {
    s = DECAY * s + GAIN * ldb4(rp + (size_t)(w0 + i) * NC);
    fw[i] = s;
  }
  s = (f32x4){0.f, 0.f, 0.f, 0.f};
  {
    int wend = w0 + 31 > 95 ? 95 : w0 + 31;
    for (int w = wend; w >= w0 + 16; --w)
      s = DECAY * s + GAIN * ldb4(rp + (size_t)w * NC);
  }
#pragma unroll
  for (int i = 15; i >= 0; --i) {
    s = DECAY * s + GAIN * ldb4(rp + (size_t)(w0 + i) * NC);
    stb4(ap + (size_t)(w0 + i) * NC, fw[i] + s);
  }
}

// -- vertical scans + final mix: acc = loc + 0.25*(acc + tb + bt) (bf16) -----
__global__ __launch_bounds__(256) void vscan_kernel(
    const unsigned short* __restrict__ loc, unsigned short* __restrict__ acc) {
  int t = blockIdx.x * 256 + threadIdx.x;      // 8*96*96*6 = 442368
  int c4 = t % 96;
  int w = (t / 96) % 96;
  int hseg = (t / 9216) % 6;
  int b = t / 55296;
  const size_t base = ((size_t)(b * NH) * NW + w) * NC + c4 * 4;
  const size_t hst = (size_t)NW * NC;
  const unsigned short* lp = loc + base;
  unsigned short* ap = acc + base;
  const int h0 = hseg * 16;

  f32x4 s = {0.f, 0.f, 0.f, 0.f};
  for (int h = (h0 >= 16 ? h0 - 16 : 0); h < h0; ++h)
    s = DECAY * s + GAIN * ldb4(lp + (size_t)h * hst);
  f32x4 tv[16];
#pragma unroll
  for (int i = 0; i < 16; ++i) {
    s = DECAY * s + GAIN * ldb4(lp + (size_t)(h0 + i) * hst);
    tv[i] = s;
  }
  s = (f32x4){0.f, 0.f, 0.f, 0.f};
  {
    int hend = h0 + 31 > 95 ? 95 : h0 + 31;
    for (int h = hend; h >= h0 + 16; --h)
      s = DECAY * s + GAIN * ldb4(lp + (size_t)h * hst);
  }
#pragma unroll
  for (int i = 15; i >= 0; --i) {
    size_t o = (size_t)(h0 + i) * hst;
    f32x4 xv = ldb4(lp + o);
    s = DECAY * s + GAIN * xv;
    f32x4 av = ldb4(ap + o);
    stb4(ap + o, xv + 0.25f * (av + tv[i] + s));
  }
}

// ---------------- layernorm over C, wave per position, bf16->bf16 -----------
__global__ __launch_bounds__(384) void ln_kernel(
    const unsigned short* __restrict__ mixed, const float* __restrict__ g,
    const float* __restrict__ bb, unsigned short* __restrict__ nrm) {
  int wv = threadIdx.x >> 6, lane = threadIdx.x & 63;
  size_t m = (size_t)blockIdx.x * 6 + wv;
  const int cb = lane * 6;
  const unsigned short* row = mixed + m * NC + cb;
  float v[6];
  {
    ushort2 a = *reinterpret_cast<const ushort2*>(row);
    ushort2 b2 = *reinterpret_cast<const ushort2*>(row + 2);
    ushort2 c = *reinterpret_cast<const ushort2*>(row + 4);
    v[0] = bf2f(a.x); v[1] = bf2f(a.y);
    v[2] = bf2f(b2.x); v[3] = bf2f(b2.y);
    v[4] = bf2f(c.x); v[5] = bf2f(c.y);
  }
  float s = 0.f, s2 = 0.f;
#pragma unroll
  for (int i = 0; i < 6; ++i) { s += v[i]; s2 += v[i] * v[i]; }
#pragma unroll
  for (int o = 32; o > 0; o >>= 1) {
    s += __shfl_xor(s, o, 64);
    s2 += __shfl_xor(s2, o, 64);
  }
  float mu = s * (1.f / NC);
  float r = rsqrtf(s2 * (1.f / NC) - mu * mu + 1e-5f);
  unsigned short o6[6];
#pragma unroll
  for (int i = 0; i < 6; ++i)
    o6[i] = f2bf((v[i] - mu) * r * g[cb + i] + bb[cb + i]);
  unsigned short* op = nrm + m * NC + cb;
  *reinterpret_cast<ushort2*>(op)     = (ushort2){o6[0], o6[1]};
  *reinterpret_cast<ushort2*>(op + 2) = (ushort2){o6[2], o6[3]};
  *reinterpret_cast<ushort2*>(op + 4) = (ushort2){o6[4], o6[5]};
}

extern "C" void kernel_launch(void* const* d_in, const int* in_sizes, int n_in,
                              void* d_out, int out_size, void* d_ws, size_t ws_size,
                              hipStream_t stream) {
  const float* x    = (const float*)d_in[0];
  const float* W_in = (const float*)d_in[1];
  const float* b_in = (const float*)d_in[2];
  const float* cw   = (const float*)d_in[3];
  const float* ln_g = (const float*)d_in[4];
  const float* ln_b = (const float*)d_in[5];
  const float* W_out= (const float*)d_in[6];
  const float* b_out= (const float*)d_in[7];
  float* out = (float*)d_out;

  // bf16 workspace layout (ushort element offsets); total ~198 MB
  unsigned short* wsu  = (unsigned short*)d_ws;
  unsigned short* xb   = wsu;                          // 14,155,776
  unsigned short* proj = wsu + 14155776;               // 28,311,552
  unsigned short* loc  = proj + 28311552;              // 28,311,552
  unsigned short* acc  = loc + 28311552;               // 28,311,552 (lr+rl, then mixed)
  unsigned short* WtI  = acc + 28311552;               // 73,728
  unsigned short* WtO  = WtI + 73728;                  // 73,728
  unsigned short* nb   = loc;                          // reuse loc after vscan

  // 1) conversions for in_proj
  cvt_x_kernel<<<(NPOS * ND / 4) / 256, 256, 0, stream>>>(x, xb);
  cvt_wi_kernel<<<(ND * NC + 255) / 256, 256, 0, stream>>>(W_in, WtI);
  // 2) in_proj MFMA GEMM -> bf16 proj   [M=73728, K=192, N=384]
  {
    dim3 g(NPOS / 128, NC / 128);
    gemm_kernel<ND, NC, 128, true><<<g, 256, 0, stream>>>(xb, WtI, b_in, proj);
  }
  // 3) depthwise conv bf16->bf16
  dwconv_kernel<<<(unsigned)((NELEM / 8) / 256), 256, 0, stream>>>(proj, cw, loc);
  // 4) horizontal EMA (lr+rl) -> acc bf16
  hscan_kernel<<<(NB * NH * 96 * 6) / 256, 256, 0, stream>>>(loc, acc);
  // 5) vertical EMA + final mix -> acc bf16 (in place)
  vscan_kernel<<<(NB * NW * 96 * 6) / 256, 256, 0, stream>>>(loc, acc);
  // 6) W_out^T bf16
  cvt_wo_kernel<<<(NC * ND + 255) / 256, 256, 0, stream>>>(W_out, WtO);
  // 7) layernorm -> bf16 normed (into loc region)
  ln_kernel<<<NPOS / 6, 384, 0, stream>>>(acc, ln_g, ln_b, nb);
  // 8) out_proj MFMA GEMM -> f32 out   [M=73728, K=384, N=192]
  {
    dim3 g(NPOS / 128, ND / 64);
    gemm_kernel<NC, ND, 64, false><<<g, 256, 0, stream>>>(nb, WtO, b_out, out);
  }
}

// Round 5
// 245.080 us; speedup vs baseline: 4.4286x; 1.2311x over previous
//
#include <hip/hip_runtime.h>
#include <hip/hip_bf16.h>

// Problem constants (LegacyScan2DOperator): B=8, H=96, W=96, D=192, C=384.
#define NB 8
#define NH 96
#define NW 96
#define ND 192
#define NC 384
#define NPOS (NB*NH*NW)            // 73728 spatial positions
#define NELEM ((size_t)NPOS*NC)    // 28,311,552 proj/local elements

#define DECAY 0.6f
#define GAIN 0.4f

typedef __attribute__((ext_vector_type(8))) short bf16x8;
typedef __attribute__((ext_vector_type(4))) float f32x4;
typedef __attribute__((ext_vector_type(4))) unsigned short us4;

__device__ inline unsigned short f2bf(float f) {
  unsigned u = __float_as_uint(f);
  u += 0x7fff + ((u >> 16) & 1);          // RNE
  return (unsigned short)(u >> 16);
}
__device__ inline float bf2f(unsigned short u) {
  return __uint_as_float((unsigned)u << 16);
}

__device__ inline void gload16(const void* g, void* l) {
  __builtin_amdgcn_global_load_lds(
      (const __attribute__((address_space(1))) void*)g,
      (__attribute__((address_space(3))) void*)l, 16, 0, 0);
}

__device__ inline f32x4 ldf4(const float* p) {
  return *reinterpret_cast<const f32x4*>(p);
}
__device__ inline f32x4 ldb4(const unsigned short* p) {
  us4 v = *reinterpret_cast<const us4*>(p);
  return (f32x4){bf2f(v.x), bf2f(v.y), bf2f(v.z), bf2f(v.w)};
}
__device__ inline void stb4(unsigned short* p, f32x4 v) {
  us4 o = {f2bf(v[0]), f2bf(v[1]), f2bf(v[2]), f2bf(v[3])};
  *reinterpret_cast<us4*>(p) = o;
}

// ---------------- conversions ----------------------------------------------
__global__ __launch_bounds__(256) void cvt_x_kernel(
    const float* __restrict__ x, unsigned short* __restrict__ xb) {
  size_t i = ((size_t)blockIdx.x * 256 + threadIdx.x) * 4;
  float4 v = *reinterpret_cast<const float4*>(&x[i]);
  ushort4 o = make_ushort4(f2bf(v.x), f2bf(v.y), f2bf(v.z), f2bf(v.w));
  *reinterpret_cast<ushort4*>(&xb[i]) = o;
}

// W_in [K=192][C=384] -> WtI [384][192] bf16
__global__ __launch_bounds__(256) void cvt_wi_kernel(
    const float* __restrict__ W, unsigned short* __restrict__ Wt) {
  int idx = blockIdx.x * 256 + threadIdx.x;
  if (idx >= ND * NC) return;
  int k = idx / NC, c = idx % NC;
  Wt[c * ND + k] = f2bf(W[idx]);
}

// W_out [K=384][D=192] -> WtO [192][384] bf16
__global__ __launch_bounds__(256) void cvt_wo_kernel(
    const float* __restrict__ W, unsigned short* __restrict__ Wt) {
  int idx = blockIdx.x * 256 + threadIdx.x;
  if (idx >= NC * ND) return;
  int k = idx / ND, d = idx % ND;
  Wt[d * NC + k] = f2bf(W[idx]);
}

// ---------------- MFMA GEMM: C[M][N] = A[M][K] @ Bt[N][K]^T + bias ----------
template<int K, int N, int BN, bool WRITE_BF16>
__global__ __launch_bounds__(256) void gemm_kernel(
    const unsigned short* __restrict__ A,
    const unsigned short* __restrict__ Bt,
    const float* __restrict__ bias,
    void* __restrict__ Cv) {
  constexpr int NF = BN / 32;
  constexpr int BSLOTS = 4 * BN;
  __shared__ __align__(16) unsigned short lsA[4 * 128 * 8];
  __shared__ __align__(16) unsigned short lsB[BSLOTS * 8];

  const int tid = threadIdx.x;
  const int lane = tid & 63;
  const int wid = tid >> 6;
  const int wm = wid >> 1, wn = wid & 1;
  const int kg = lane >> 4, r16 = lane & 15;
  const int m0 = blockIdx.x * 128;
  const int n0 = blockIdx.y * BN;

  const int sa0 = tid, sa1 = tid + 256;
  const unsigned short* srcA0 = A + (size_t)(m0 + (sa0 & 127)) * K + (sa0 >> 7) * 8;
  const unsigned short* srcA1 = A + (size_t)(m0 + (sa1 & 127)) * K + (sa1 >> 7) * 8;
  const unsigned short* srcB0 = Bt + (size_t)(n0 + (tid & (BN - 1))) * K + (tid / BN) * 8;
  const unsigned short* srcBh = Bt;
  if constexpr (BN == 128) {
    const int sb1 = tid + 256;
    srcBh = Bt + (size_t)(n0 + (sb1 & 127)) * K + (sb1 >> 7) * 8;
  }

  int aoff[4], boff[NF];
#pragma unroll
  for (int m = 0; m < 4; ++m)
    aoff[m] = (kg * 128 + wm * 64 + m * 16 + r16) * 8;
#pragma unroll
  for (int n = 0; n < NF; ++n)
    boff[n] = (kg * BN + wn * (BN / 2) + n * 16 + r16) * 8;

  f32x4 acc[4][NF];
  float bv[NF];
#pragma unroll
  for (int n = 0; n < NF; ++n) bv[n] = bias[n0 + wn * (BN / 2) + n * 16 + r16];
#pragma unroll
  for (int m = 0; m < 4; ++m)
#pragma unroll
    for (int n = 0; n < NF; ++n)
      acc[m][n] = (f32x4){bv[n], bv[n], bv[n], bv[n]};

  for (int ks = 0; ks < K / 32; ++ks) {
    const int ke = ks * 32;
    gload16(srcA0 + ke, &lsA[sa0 * 8]);
    gload16(srcA1 + ke, &lsA[sa1 * 8]);
    gload16(srcB0 + ke, &lsB[tid * 8]);
    if constexpr (BN == 128) gload16(srcBh + ke, &lsB[(tid + 256) * 8]);
    __syncthreads();
    bf16x8 af[4], bfr[NF];
#pragma unroll
    for (int m = 0; m < 4; ++m)
      af[m] = *reinterpret_cast<const bf16x8*>(&lsA[aoff[m]]);
#pragma unroll
    for (int n = 0; n < NF; ++n)
      bfr[n] = *reinterpret_cast<const bf16x8*>(&lsB[boff[n]]);
#pragma unroll
    for (int m = 0; m < 4; ++m)
#pragma unroll
      for (int n = 0; n < NF; ++n)
        acc[m][n] = __builtin_amdgcn_mfma_f32_16x16x32_bf16(af[m], bfr[n], acc[m][n], 0, 0, 0);
    __syncthreads();
  }

#pragma unroll
  for (int m = 0; m < 4; ++m) {
    const int row = m0 + wm * 64 + m * 16 + kg * 4;
#pragma unroll
    for (int n = 0; n < NF; ++n) {
      const int col = n0 + wn * (BN / 2) + n * 16 + r16;
#pragma unroll
      for (int j = 0; j < 4; ++j) {
        if constexpr (WRITE_BF16)
          ((unsigned short*)Cv)[(size_t)(row + j) * N + col] = f2bf(acc[m][n][j]);
        else
          ((float*)Cv)[(size_t)(row + j) * N + col] = acc[m][n][j];
      }
    }
  }
}

// ------- depthwise 3x3 SAME conv, sliding-window, 16 outputs/thread ---------
// thread = (b*NH+h, wseg, c4); keeps 3x3 column window in registers.
__global__ __launch_bounds__(256) void dwconv_kernel(
    const unsigned short* __restrict__ proj, const float* __restrict__ cw,
    unsigned short* __restrict__ loc) {
  int t = blockIdx.x * 256 + threadIdx.x;   // 8*96*6*96 = 442368
  int c4 = t % 96;
  int wseg = (t / 96) % 6;
  int bh = t / 576;                          // b*NH + h
  int h = bh % NH;
  const int w0 = wseg * 16;

  // weights for 4 channels, transposed to tap-major
  f32x4 raw[9];
  const float* cwp = cw + (size_t)c4 * 36;
#pragma unroll
  for (int i = 0; i < 9; ++i) raw[i] = ldf4(cwp + i * 4);
  f32x4 qq[9];
#pragma unroll
  for (int tap = 0; tap < 9; ++tap)
#pragma unroll
    for (int c = 0; c < 4; ++c)
      qq[tap][c] = raw[(c * 9 + tap) >> 2][(c * 9 + tap) & 3];

  const bool hm = (h > 0), hp = (h < NH - 1);
  const unsigned short* rowm = proj + ((size_t)(bh - 1) * NW) * NC + c4 * 4;
  const unsigned short* rowc = proj + ((size_t)bh * NW) * NC + c4 * 4;
  const unsigned short* rowp = proj + ((size_t)(bh + 1) * NW) * NC + c4 * 4;
  unsigned short* op = loc + ((size_t)bh * NW) * NC + c4 * 4;

  const f32x4 z = {0.f, 0.f, 0.f, 0.f};
  f32x4 colL[3], colC[3], colR[3];
  if (w0 > 0) {
    colL[0] = hm ? ldb4(rowm + (size_t)(w0 - 1) * NC) : z;
    colL[1] = ldb4(rowc + (size_t)(w0 - 1) * NC);
    colL[2] = hp ? ldb4(rowp + (size_t)(w0 - 1) * NC) : z;
  } else { colL[0] = z; colL[1] = z; colL[2] = z; }
  colC[0] = hm ? ldb4(rowm + (size_t)w0 * NC) : z;
  colC[1] = ldb4(rowc + (size_t)w0 * NC);
  colC[2] = hp ? ldb4(rowp + (size_t)w0 * NC) : z;

#pragma unroll
  for (int i = 0; i < 16; ++i) {
    const int w = w0 + i;
    if (w + 1 < NW) {
      colR[0] = hm ? ldb4(rowm + (size_t)(w + 1) * NC) : z;
      colR[1] = ldb4(rowc + (size_t)(w + 1) * NC);
      colR[2] = hp ? ldb4(rowp + (size_t)(w + 1) * NC) : z;
    } else { colR[0] = z; colR[1] = z; colR[2] = z; }
    f32x4 a = colL[0] * qq[0] + colC[0] * qq[1] + colR[0] * qq[2]
            + colL[1] * qq[3] + colC[1] * qq[4] + colR[1] * qq[5]
            + colL[2] * qq[6] + colC[2] * qq[7] + colR[2] * qq[8];
    stb4(op + (size_t)w * NC, a);
    colL[0] = colC[0]; colL[1] = colC[1]; colL[2] = colC[2];
    colC[0] = colR[0]; colC[1] = colR[1]; colC[2] = colR[2];
  }
}

// ------------- horizontal scans, segmented: acc = lr + rl (bf16) ------------
__global__ __launch_bounds__(256) void hscan_kernel(
    const unsigned short* __restrict__ loc, unsigned short* __restrict__ acc) {
  int t = blockIdx.x * 256 + threadIdx.x;      // 768*96*6 = 442368
  int c4 = t % 96;
  int seg = (t / 96) % 6;
  int bh = t / 576;
  const size_t base = (size_t)bh * (NW * NC) + c4 * 4;
  const unsigned short* rp = loc + base;
  unsigned short* ap = acc + base;
  const int w0 = seg * 16;

  f32x4 s = {0.f, 0.f, 0.f, 0.f};
  for (int w = (w0 >= 16 ? w0 - 16 : 0); w < w0; ++w)
    s = DECAY * s + GAIN * ldb4(rp + (size_t)w * NC);
  f32x4 fw[16];
#pragma unroll
  for (int i = 0; i < 16; ++i) {
    s = DECAY * s + GAIN * ldb4(rp + (size_t)(w0 + i) * NC);
    fw[i] = s;
  }
  s = (f32x4){0.f, 0.f, 0.f, 0.f};
  {
    int wend = w0 + 31 > 95 ? 95 : w0 + 31;
    for (int w = wend; w >= w0 + 16; --w)
      s = DECAY * s + GAIN * ldb4(rp + (size_t)w * NC);
  }
#pragma unroll
  for (int i = 15; i >= 0; --i) {
    s = DECAY * s + GAIN * ldb4(rp + (size_t)(w0 + i) * NC);
    stb4(ap + (size_t)(w0 + i) * NC, fw[i] + s);
  }
}

// -- fused: vertical scans + final mix + layernorm -> bf16 normed ------------
// block = (b, w); 576 threads = (c4 0..95, hseg 0..5); mixed tile in LDS.
__global__ __launch_bounds__(576) void vscan_ln_kernel(
    const unsigned short* __restrict__ loc, const unsigned short* __restrict__ acc,
    const float* __restrict__ g, const float* __restrict__ bb,
    unsigned short* __restrict__ nrm) {
  __shared__ unsigned short mix[NH * NC];        // 96*384*2B = 73.7 KB
  const int tid = threadIdx.x;
  const int c4 = tid % 96;
  const int hseg = tid / 96;                     // [0,6)
  const int w = blockIdx.x % NW;
  const int b = blockIdx.x / NW;
  const size_t base = ((size_t)(b * NH) * NW + w) * NC + c4 * 4;
  const size_t hst = (size_t)NW * NC;
  const unsigned short* lp = loc + base;
  const unsigned short* ap = acc + base;
  const int h0 = hseg * 16;

  f32x4 s = {0.f, 0.f, 0.f, 0.f};
  for (int h = (h0 >= 16 ? h0 - 16 : 0); h < h0; ++h)
    s = DECAY * s + GAIN * ldb4(lp + (size_t)h * hst);
  f32x4 tv[16];
#pragma unroll
  for (int i = 0; i < 16; ++i) {
    s = DECAY * s + GAIN * ldb4(lp + (size_t)(h0 + i) * hst);
    tv[i] = s;
  }
  s = (f32x4){0.f, 0.f, 0.f, 0.f};
  {
    int hend = h0 + 31 > 95 ? 95 : h0 + 31;
    for (int h = hend; h >= h0 + 16; --h)
      s = DECAY * s + GAIN * ldb4(lp + (size_t)h * hst);
  }
#pragma unroll
  for (int i = 15; i >= 0; --i) {
    size_t o = (size_t)(h0 + i) * hst;
    f32x4 xv = ldb4(lp + o);
    s = DECAY * s + GAIN * xv;
    f32x4 av = ldb4(ap + o);
    f32x4 mx = xv + 0.25f * (av + tv[i] + s);
    us4 m4 = {f2bf(mx[0]), f2bf(mx[1]), f2bf(mx[2]), f2bf(mx[3])};
    *reinterpret_cast<us4*>(&mix[(h0 + i) * NC + c4 * 4]) = m4;
  }
  __syncthreads();

  // LN phase: 9 waves, wave-per-row over LDS
  const int wave = tid >> 6, lane = tid & 63;
  const int cb = lane * 6;
  float gv[6], bv[6];
#pragma unroll
  for (int i = 0; i < 6; ++i) { gv[i] = g[cb + i]; bv[i] = bb[cb + i]; }
  for (int h = wave; h < NH; h += 9) {
    const unsigned short* row = &mix[h * NC + cb];
    float v[6];
    {
      ushort2 a2 = *reinterpret_cast<const ushort2*>(row);
      ushort2 b2 = *reinterpret_cast<const ushort2*>(row + 2);
      ushort2 c2 = *reinterpret_cast<const ushort2*>(row + 4);
      v[0] = bf2f(a2.x); v[1] = bf2f(a2.y);
      v[2] = bf2f(b2.x); v[3] = bf2f(b2.y);
      v[4] = bf2f(c2.x); v[5] = bf2f(c2.y);
    }
    float sm = 0.f, s2 = 0.f;
#pragma unroll
    for (int i = 0; i < 6; ++i) { sm += v[i]; s2 += v[i] * v[i]; }
#pragma unroll
    for (int o = 32; o > 0; o >>= 1) {
      sm += __shfl_xor(sm, o, 64);
      s2 += __shfl_xor(s2, o, 64);
    }
    float mu = sm * (1.f / NC);
    float r = rsqrtf(s2 * (1.f / NC) - mu * mu + 1e-5f);
    unsigned short o6[6];
#pragma unroll
    for (int i = 0; i < 6; ++i)
      o6[i] = f2bf((v[i] - mu) * r * gv[i] + bv[i]);
    unsigned short* op = nrm + ((size_t)(b * NH + h) * NW + w) * NC + cb;
    *reinterpret_cast<ushort2*>(op)     = (ushort2){o6[0], o6[1]};
    *reinterpret_cast<ushort2*>(op + 2) = (ushort2){o6[2], o6[3]};
    *reinterpret_cast<ushort2*>(op + 4) = (ushort2){o6[4], o6[5]};
  }
}

extern "C" void kernel_launch(void* const* d_in, const int* in_sizes, int n_in,
                              void* d_out, int out_size, void* d_ws, size_t ws_size,
                              hipStream_t stream) {
  const float* x    = (const float*)d_in[0];
  const float* W_in = (const float*)d_in[1];
  const float* b_in = (const float*)d_in[2];
  const float* cw   = (const float*)d_in[3];
  const float* ln_g = (const float*)d_in[4];
  const float* ln_b = (const float*)d_in[5];
  const float* W_out= (const float*)d_in[6];
  const float* b_out= (const float*)d_in[7];
  float* out = (float*)d_out;

  // bf16 workspace layout (ushort element offsets); total ~198 MB
  unsigned short* wsu  = (unsigned short*)d_ws;
  unsigned short* xb   = wsu;                          // 14,155,776
  unsigned short* proj = wsu + 14155776;               // 28,311,552
  unsigned short* loc  = proj + 28311552;              // 28,311,552
  unsigned short* acc  = loc + 28311552;               // 28,311,552 (lr+rl)
  unsigned short* WtI  = acc + 28311552;               // 73,728
  unsigned short* WtO  = WtI + 73728;                  // 73,728
  unsigned short* nb   = loc;   // normed aliases loc (per-(b,w) column, safe)

  // 1) conversions for in_proj
  cvt_x_kernel<<<(NPOS * ND / 4) / 256, 256, 0, stream>>>(x, xb);
  cvt_wi_kernel<<<(ND * NC + 255) / 256, 256, 0, stream>>>(W_in, WtI);
  // 2) in_proj MFMA GEMM -> bf16 proj   [M=73728, K=192, N=384]
  {
    dim3 g(NPOS / 128, NC / 128);
    gemm_kernel<ND, NC, 128, true><<<g, 256, 0, stream>>>(xb, WtI, b_in, proj);
  }
  // 3) depthwise conv bf16->bf16 (sliding window)
  dwconv_kernel<<<(NB * NH * 6 * 96) / 256, 256, 0, stream>>>(proj, cw, loc);
  // 4) horizontal EMA (lr+rl) -> acc bf16
  hscan_kernel<<<(NB * NH * 96 * 6) / 256, 256, 0, stream>>>(loc, acc);
  // 5) W_out^T bf16
  cvt_wo_kernel<<<(NC * ND + 255) / 256, 256, 0, stream>>>(W_out, WtO);
  // 6) fused vertical EMA + mix + layernorm -> bf16 normed
  vscan_ln_kernel<<<NB * NW, 576, 0, stream>>>(loc, acc, ln_g, ln_b, nb);
  // 7) out_proj MFMA GEMM -> f32 out   [M=73728, K=384, N=192]
  {
    dim3 g(NPOS / 128, ND / 64);
    gemm_kernel<NC, ND, 64, false><<<g, 256, 0, stream>>>(nb, WtO, b_out, out);
  }
}